// Round 1
// baseline (590.703 us; speedup 1.0000x reference)
//
#include <hip/hip_runtime.h>

#define NN 50000
#define EE 800000
#define FF 64
#define HH 4
#define HF 256          // H*F
#define NEG_SLOPE 0.2f
#define LN_EPS 1e-5f

// ---------------- Kernel A: feat = h @ fc_w ; el/er per (node, head) -------
__global__ __launch_bounds__(256) void k_feat(
    const float* __restrict__ h, const float* __restrict__ fc_w,
    const float* __restrict__ attn_l, const float* __restrict__ attn_r,
    float* __restrict__ feat, float* __restrict__ el, float* __restrict__ er) {
  __shared__ float wlds[FF * HF];  // 64 KB
  for (int i = threadIdx.x; i < FF * HF; i += 256) wlds[i] = fc_w[i];
  __syncthreads();
  const int c = threadIdx.x;       // 0..255 = head*64 + f
  const int head = c >> 6;
  const int f = c & 63;
  const float al = attn_l[c];      // attn_l[head][f]
  const float ar = attn_r[c];
  for (int n = blockIdx.x; n < NN; n += gridDim.x) {
    const float* hr = h + (size_t)n * FF;
    float acc = 0.f;
#pragma unroll
    for (int k = 0; k < FF; ++k) acc = fmaf(hr[k], wlds[k * HF + c], acc);
    feat[(size_t)n * HF + c] = acc;
    float vl = acc * al, vr = acc * ar;
#pragma unroll
    for (int off = 32; off > 0; off >>= 1) {
      vl += __shfl_down(vl, off, 64);
      vr += __shfl_down(vr, off, 64);
    }
    if (f == 0) {
      el[n * HH + head] = vl;
      er[n * HH + head] = vr;
    }
  }
}

// ---------------- CSR build ------------------------------------------------
__global__ void k_hist(const int* __restrict__ dst, int* __restrict__ deg) {
  int e = blockIdx.x * blockDim.x + threadIdx.x;
  if (e < EE) atomicAdd(&deg[dst[e]], 1);
}

__global__ __launch_bounds__(1024) void k_scan(
    const int* __restrict__ deg, int* __restrict__ row_ptr,
    int* __restrict__ cursor) {
  __shared__ int sums[1024];
  const int t = threadIdx.x;
  const int chunk = (NN + 1023) / 1024;
  int lo = t * chunk, hi = lo + chunk;
  if (lo > NN) lo = NN;
  if (hi > NN) hi = NN;
  int s = 0;
  for (int i = lo; i < hi; ++i) s += deg[i];
  sums[t] = s;
  __syncthreads();
  for (int off = 1; off < 1024; off <<= 1) {
    int u = (t >= off) ? sums[t - off] : 0;
    __syncthreads();
    sums[t] += u;
    __syncthreads();
  }
  int run = sums[t] - s;  // exclusive prefix of this thread's chunk
  for (int i = lo; i < hi; ++i) {
    row_ptr[i] = run;
    cursor[i] = run;
    run += deg[i];
  }
  if (t == 1023) row_ptr[NN] = sums[1023];
}

__global__ void k_scatter(const int* __restrict__ src,
                          const int* __restrict__ dst,
                          int* __restrict__ cursor, int* __restrict__ col) {
  int e = blockIdx.x * blockDim.x + threadIdx.x;
  if (e < EE) {
    int pos = atomicAdd(&cursor[dst[e]], 1);
    col[pos] = src[e];
  }
}

// ---------------- Kernel C: per-node softmax-weighted gather ---------------
// One wave per dst node. lane = f; 4 head accumulators per lane.
// alpha = w/z folded as rst = (sum w*feat)/(sum w)  (max-shift is a no-op).
__global__ __launch_bounds__(256) void k_gather(
    const float* __restrict__ feat, const float* __restrict__ el,
    const float* __restrict__ er, const int* __restrict__ row_ptr,
    const int* __restrict__ col, const float* __restrict__ gat_bias,
    float* __restrict__ rst) {
  const int wave = threadIdx.x >> 6;
  const int lane = threadIdx.x & 63;
  const int gw = blockIdx.x * 4 + wave;
  const int stride = gridDim.x * 4;
  const float gb0 = gat_bias[lane], gb1 = gat_bias[64 + lane];
  const float gb2 = gat_bias[128 + lane], gb3 = gat_bias[192 + lane];
  for (int n = gw; n < NN; n += stride) {
    const int lo = row_ptr[n], hi = row_ptr[n + 1];
    const float4 erv = *(const float4*)(er + (size_t)n * 4);
    float a0 = 0.f, a1 = 0.f, a2 = 0.f, a3 = 0.f;
    float z0 = 0.f, z1 = 0.f, z2 = 0.f, z3 = 0.f;
    for (int idx = lo; idx < hi; ++idx) {
      const int s = col[idx];
      const float4 elv = *(const float4*)(el + (size_t)s * 4);
      float e0 = elv.x + erv.x, e1 = elv.y + erv.y;
      float e2 = elv.z + erv.z, e3 = elv.w + erv.w;
      e0 = e0 > 0.f ? e0 : NEG_SLOPE * e0;
      e1 = e1 > 0.f ? e1 : NEG_SLOPE * e1;
      e2 = e2 > 0.f ? e2 : NEG_SLOPE * e2;
      e3 = e3 > 0.f ? e3 : NEG_SLOPE * e3;
      const float w0 = __expf(e0), w1 = __expf(e1);
      const float w2 = __expf(e2), w3 = __expf(e3);
      z0 += w0; z1 += w1; z2 += w2; z3 += w3;
      const float* fp = feat + (size_t)s * HF + lane;
      a0 = fmaf(w0, fp[0], a0);
      a1 = fmaf(w1, fp[64], a1);
      a2 = fmaf(w2, fp[128], a2);
      a3 = fmaf(w3, fp[192], a3);
    }
    float* rp = rst + (size_t)n * HF + lane;
    rp[0]   = (z0 > 0.f ? a0 / z0 : 0.f) + gb0;
    rp[64]  = (z1 > 0.f ? a1 / z1 : 0.f) + gb1;
    rp[128] = (z2 > 0.f ? a2 / z2 : 0.f) + gb2;
    rp[192] = (z3 > 0.f ? a3 / z3 : 0.f) + gb3;
  }
}

// ---------------- Kernel D: x = rst @ out_w + out_b ; LayerNorm ------------
// Block: out_w in LDS [k][c]. Wave handles 8 nodes (N%8==0), lane = col.
// rst row addresses are wave-uniform -> scalar loads.
__global__ __launch_bounds__(256) void k_out(
    const float* __restrict__ rst, const float* __restrict__ out_w,
    const float* __restrict__ out_b, const float* __restrict__ ln_g,
    const float* __restrict__ ln_b, float* __restrict__ out) {
  __shared__ float wlds[HF * FF];  // 64 KB
  for (int i = threadIdx.x; i < HF * FF; i += 256) wlds[i] = out_w[i];
  __syncthreads();
  const int wave = threadIdx.x >> 6;
  const int lane = threadIdx.x & 63;
  const float ob = out_b[lane], g = ln_g[lane], bb = ln_b[lane];
  for (int n0 = blockIdx.x * 32 + wave * 8; n0 < NN; n0 += gridDim.x * 32) {
    float acc[8];
#pragma unroll
    for (int j = 0; j < 8; ++j) acc[j] = ob;
    const float* r0 = rst + (size_t)n0 * HF;
#pragma unroll 4
    for (int k = 0; k < HF; ++k) {
      const float wv = wlds[k * FF + lane];
#pragma unroll
      for (int j = 0; j < 8; ++j) acc[j] = fmaf(r0[j * HF + k], wv, acc[j]);
    }
#pragma unroll
    for (int j = 0; j < 8; ++j) {
      const float x = acc[j];
      float s1 = x, s2 = x * x;
#pragma unroll
      for (int off = 32; off > 0; off >>= 1) {
        s1 += __shfl_xor(s1, off, 64);
        s2 += __shfl_xor(s2, off, 64);
      }
      const float mu = s1 * (1.f / 64.f);
      const float var = s2 * (1.f / 64.f) - mu * mu;
      const float inv = rsqrtf(var + LN_EPS);
      out[(size_t)(n0 + j) * FF + lane] = (x - mu) * inv * g + bb;
    }
  }
}

// ---------------- launch ---------------------------------------------------
extern "C" void kernel_launch(void* const* d_in, const int* in_sizes, int n_in,
                              void* d_out, int out_size, void* d_ws,
                              size_t ws_size, hipStream_t stream) {
  const float* h_in   = (const float*)d_in[0];
  const int*   src    = (const int*)d_in[1];
  const int*   dst    = (const int*)d_in[2];
  const float* fc_w   = (const float*)d_in[3];
  const float* attn_l = (const float*)d_in[4];
  const float* attn_r = (const float*)d_in[5];
  const float* gbias  = (const float*)d_in[6];
  const float* out_w  = (const float*)d_in[7];
  const float* out_b  = (const float*)d_in[8];
  const float* ln_g   = (const float*)d_in[9];
  const float* ln_b   = (const float*)d_in[10];
  float* out = (float*)d_out;

  char* p = (char*)d_ws;
  auto alloc = [&](size_t bytes) {
    char* q = p;
    p += (bytes + 255) & ~(size_t)255;
    return q;
  };
  float* feat    = (float*)alloc((size_t)NN * HF * 4);
  float* el      = (float*)alloc((size_t)NN * HH * 4);
  float* er      = (float*)alloc((size_t)NN * HH * 4);
  float* rst     = (float*)alloc((size_t)NN * HF * 4);
  int*   deg     = (int*)alloc((size_t)NN * 4);
  int*   row_ptr = (int*)alloc((size_t)(NN + 1) * 4);
  int*   cursor  = (int*)alloc((size_t)NN * 4);
  int*   colidx  = (int*)alloc((size_t)EE * 4);

  hipMemsetAsync(deg, 0, (size_t)NN * sizeof(int), stream);
  k_feat<<<512, 256, 0, stream>>>(h_in, fc_w, attn_l, attn_r, feat, el, er);
  k_hist<<<(EE + 255) / 256, 256, 0, stream>>>(dst, deg);
  k_scan<<<1, 1024, 0, stream>>>(deg, row_ptr, cursor);
  k_scatter<<<(EE + 255) / 256, 256, 0, stream>>>(src, dst, cursor, colidx);
  k_gather<<<2048, 256, 0, stream>>>(feat, el, er, row_ptr, colidx, gbias, rst);
  k_out<<<512, 256, 0, stream>>>(rst, out_w, out_b, ln_g, ln_b, out);
}

// Round 2
// 558.431 us; speedup vs baseline: 1.0578x; 1.0578x over previous
//
#include <hip/hip_runtime.h>

#define NN 50000
#define EE 800000
#define FF 64
#define HH 4
#define HF 256          // H*F
#define NEG_SLOPE 0.2f
#define LN_EPS 1e-5f

__device__ __forceinline__ unsigned short f32_to_bf16_rne(float x) {
  unsigned int u = __float_as_uint(x);
  unsigned int r = u + 0x7FFFu + ((u >> 16) & 1u);
  return (unsigned short)(r >> 16);
}

// ---------------- Kernel A: feat = h @ fc_w ; el/er per (node, head) -------
// Weight column in registers (no LDS). h-row loads are wave-uniform -> s_load.
// feat stored bf16 in layout [n][f][h] so the gather reads 4 heads per dwordx2.
__global__ __launch_bounds__(256) void k_feat(
    const float* __restrict__ h, const float* __restrict__ fc_w,
    const float* __restrict__ attn_l, const float* __restrict__ attn_r,
    unsigned short* __restrict__ featb, float* __restrict__ el,
    float* __restrict__ er) {
  const int c = threadIdx.x;       // 0..255 = head*64 + f
  const int head = c >> 6;
  const int f = c & 63;
  float wreg[FF];
#pragma unroll
  for (int k = 0; k < FF; ++k) wreg[k] = fc_w[k * HF + c];  // coalesced
  const float al = attn_l[c];
  const float ar = attn_r[c];
  for (int n = blockIdx.x; n < NN; n += gridDim.x) {
    const float* __restrict__ hr = h + (size_t)n * FF;
    float acc = 0.f;
#pragma unroll
    for (int k = 0; k < FF; ++k) acc = fmaf(hr[k], wreg[k], acc);
    featb[(size_t)n * HF + f * HH + head] = f32_to_bf16_rne(acc);
    float vl = acc * al, vr = acc * ar;
#pragma unroll
    for (int off = 32; off > 0; off >>= 1) {
      vl += __shfl_down(vl, off, 64);
      vr += __shfl_down(vr, off, 64);
    }
    if (f == 0) {
      el[n * HH + head] = vl;
      er[n * HH + head] = vr;
    }
  }
}

// ---------------- CSR build ------------------------------------------------
__global__ void k_hist(const int* __restrict__ dst, int* __restrict__ deg) {
  int e = blockIdx.x * blockDim.x + threadIdx.x;
  if (e < EE) atomicAdd(&deg[dst[e]], 1);
}

__global__ __launch_bounds__(1024) void k_scan(
    const int* __restrict__ deg, int* __restrict__ row_ptr,
    int* __restrict__ cursor) {
  __shared__ int sums[1024];
  const int t = threadIdx.x;
  const int chunk = (NN + 1023) / 1024;
  int lo = t * chunk, hi = lo + chunk;
  if (lo > NN) lo = NN;
  if (hi > NN) hi = NN;
  int s = 0;
  for (int i = lo; i < hi; ++i) s += deg[i];
  sums[t] = s;
  __syncthreads();
  for (int off = 1; off < 1024; off <<= 1) {
    int u = (t >= off) ? sums[t - off] : 0;
    __syncthreads();
    sums[t] += u;
    __syncthreads();
  }
  int run = sums[t] - s;  // exclusive prefix of this thread's chunk
  for (int i = lo; i < hi; ++i) {
    row_ptr[i] = run;
    cursor[i] = run;
    run += deg[i];
  }
  if (t == 1023) row_ptr[NN] = sums[1023];
}

__global__ void k_scatter(const int* __restrict__ src,
                          const int* __restrict__ dst,
                          int* __restrict__ cursor, int* __restrict__ col) {
  int e = blockIdx.x * blockDim.x + threadIdx.x;
  if (e < EE) {
    int pos = atomicAdd(&cursor[dst[e]], 1);
    col[pos] = src[e];
  }
}

// ---------------- Kernel C: per-node softmax-weighted gather ---------------
// One wave per dst node. lane = f. feat row is bf16 [f][h]: ONE dwordx2 per
// lane fetches all 4 heads. alpha = w/z folded (max-shift is a no-op).
__global__ __launch_bounds__(256) void k_gather(
    const unsigned short* __restrict__ featb, const float* __restrict__ el,
    const float* __restrict__ er, const int* __restrict__ row_ptr,
    const int* __restrict__ col, const float* __restrict__ gat_bias,
    float* __restrict__ rst) {
  const int wave = threadIdx.x >> 6;
  const int lane = threadIdx.x & 63;
  const int gw = blockIdx.x * 4 + wave;
  const int stride = gridDim.x * 4;
  const float gb0 = gat_bias[lane], gb1 = gat_bias[64 + lane];
  const float gb2 = gat_bias[128 + lane], gb3 = gat_bias[192 + lane];
  for (int n = gw; n < NN; n += stride) {
    const int lo = row_ptr[n], hi = row_ptr[n + 1];
    const float4 erv = *(const float4*)(er + (size_t)n * 4);
    float a0 = 0.f, a1 = 0.f, a2 = 0.f, a3 = 0.f;
    float z0 = 0.f, z1 = 0.f, z2 = 0.f, z3 = 0.f;
    for (int idx = lo; idx < hi; ++idx) {
      const int s = col[idx];                     // wave-uniform
      const float4 elv = *(const float4*)(el + (size_t)s * 4);
      float e0 = elv.x + erv.x, e1 = elv.y + erv.y;
      float e2 = elv.z + erv.z, e3 = elv.w + erv.w;
      e0 = e0 > 0.f ? e0 : NEG_SLOPE * e0;
      e1 = e1 > 0.f ? e1 : NEG_SLOPE * e1;
      e2 = e2 > 0.f ? e2 : NEG_SLOPE * e2;
      e3 = e3 > 0.f ? e3 : NEG_SLOPE * e3;
      const float w0 = __expf(e0), w1 = __expf(e1);
      const float w2 = __expf(e2), w3 = __expf(e3);
      z0 += w0; z1 += w1; z2 += w2; z3 += w3;
      const uint2 d = *(const uint2*)(featb + (size_t)s * HF + lane * HH);
      const float f0 = __uint_as_float(d.x << 16);
      const float f1 = __uint_as_float(d.x & 0xFFFF0000u);
      const float f2 = __uint_as_float(d.y << 16);
      const float f3 = __uint_as_float(d.y & 0xFFFF0000u);
      a0 = fmaf(w0, f0, a0);
      a1 = fmaf(w1, f1, a1);
      a2 = fmaf(w2, f2, a2);
      a3 = fmaf(w3, f3, a3);
    }
    float* rp = rst + (size_t)n * HF + lane;      // rst[n][h][f]
    rp[0]   = (z0 > 0.f ? a0 / z0 : 0.f) + gb0;
    rp[64]  = (z1 > 0.f ? a1 / z1 : 0.f) + gb1;
    rp[128] = (z2 > 0.f ? a2 / z2 : 0.f) + gb2;
    rp[192] = (z3 > 0.f ? a3 / z3 : 0.f) + gb3;
  }
}

// ---------------- Kernel D: x = rst @ out_w + out_b ; LayerNorm ------------
__global__ __launch_bounds__(256) void k_out(
    const float* __restrict__ rst, const float* __restrict__ out_w,
    const float* __restrict__ out_b, const float* __restrict__ ln_g,
    const float* __restrict__ ln_b, float* __restrict__ out) {
  __shared__ float wlds[HF * FF];  // 64 KB
  for (int i = threadIdx.x; i < HF * FF; i += 256) wlds[i] = out_w[i];
  __syncthreads();
  const int wave = threadIdx.x >> 6;
  const int lane = threadIdx.x & 63;
  const float ob = out_b[lane], g = ln_g[lane], bb = ln_b[lane];
  for (int n0 = blockIdx.x * 32 + wave * 8; n0 < NN; n0 += gridDim.x * 32) {
    float acc[8];
#pragma unroll
    for (int j = 0; j < 8; ++j) acc[j] = ob;
    const float* __restrict__ r0 = rst + (size_t)n0 * HF;
#pragma unroll 4
    for (int k = 0; k < HF; ++k) {
      const float wv = wlds[k * FF + lane];
#pragma unroll
      for (int j = 0; j < 8; ++j) acc[j] = fmaf(r0[j * HF + k], wv, acc[j]);
    }
#pragma unroll
    for (int j = 0; j < 8; ++j) {
      const float x = acc[j];
      float s1 = x, s2 = x * x;
#pragma unroll
      for (int off = 32; off > 0; off >>= 1) {
        s1 += __shfl_xor(s1, off, 64);
        s2 += __shfl_xor(s2, off, 64);
      }
      const float mu = s1 * (1.f / 64.f);
      const float var = s2 * (1.f / 64.f) - mu * mu;
      const float inv = rsqrtf(var + LN_EPS);
      out[(size_t)(n0 + j) * FF + lane] = (x - mu) * inv * g + bb;
    }
  }
}

// ---------------- launch ---------------------------------------------------
extern "C" void kernel_launch(void* const* d_in, const int* in_sizes, int n_in,
                              void* d_out, int out_size, void* d_ws,
                              size_t ws_size, hipStream_t stream) {
  const float* h_in   = (const float*)d_in[0];
  const int*   src    = (const int*)d_in[1];
  const int*   dst    = (const int*)d_in[2];
  const float* fc_w   = (const float*)d_in[3];
  const float* attn_l = (const float*)d_in[4];
  const float* attn_r = (const float*)d_in[5];
  const float* gbias  = (const float*)d_in[6];
  const float* out_w  = (const float*)d_in[7];
  const float* out_b  = (const float*)d_in[8];
  const float* ln_g   = (const float*)d_in[9];
  const float* ln_b   = (const float*)d_in[10];
  float* out = (float*)d_out;

  char* p = (char*)d_ws;
  auto alloc = [&](size_t bytes) {
    char* q = p;
    p += (bytes + 255) & ~(size_t)255;
    return q;
  };
  unsigned short* featb = (unsigned short*)alloc((size_t)NN * HF * 2);
  float* el      = (float*)alloc((size_t)NN * HH * 4);
  float* er      = (float*)alloc((size_t)NN * HH * 4);
  float* rst     = (float*)alloc((size_t)NN * HF * 4);
  int*   deg     = (int*)alloc((size_t)NN * 4);
  int*   row_ptr = (int*)alloc((size_t)(NN + 1) * 4);
  int*   cursor  = (int*)alloc((size_t)NN * 4);
  int*   colidx  = (int*)alloc((size_t)EE * 4);

  hipMemsetAsync(deg, 0, (size_t)NN * sizeof(int), stream);
  k_feat<<<512, 256, 0, stream>>>(h_in, fc_w, attn_l, attn_r, featb, el, er);
  k_hist<<<(EE + 255) / 256, 256, 0, stream>>>(dst, deg);
  k_scan<<<1, 1024, 0, stream>>>(deg, row_ptr, cursor);
  k_scatter<<<(EE + 255) / 256, 256, 0, stream>>>(src, dst, cursor, colidx);
  k_gather<<<2048, 256, 0, stream>>>(featb, el, er, row_ptr, colidx, gbias, rst);
  k_out<<<512, 256, 0, stream>>>(rst, out_w, out_b, ln_g, ln_b, out);
}

// Round 3
// 468.364 us; speedup vs baseline: 1.2612x; 1.1923x over previous
//
#include <hip/hip_runtime.h>

#define NN 50000
#define EE 800000
#define FF 64
#define HH 4
#define HF 256          // H*F
#define NEG_SLOPE 0.2f
#define LN_EPS 1e-5f

typedef __attribute__((ext_vector_type(8))) short s8v;    // 8 bf16 (4 VGPRs)
typedef __attribute__((ext_vector_type(4))) float f4v;    // 4 fp32 acc

__device__ __forceinline__ unsigned short f32_to_bf16_rne(float x) {
  unsigned int u = __float_as_uint(x);
  unsigned int r = u + 0x7FFFu + ((u >> 16) & 1u);
  return (unsigned short)(r >> 16);
}

// ---------------- Kernel A: feat = h @ fc_w ; el/er per (node, head) -------
__global__ __launch_bounds__(256) void k_feat(
    const float* __restrict__ h, const float* __restrict__ fc_w,
    const float* __restrict__ attn_l, const float* __restrict__ attn_r,
    unsigned short* __restrict__ featb, float* __restrict__ el,
    float* __restrict__ er) {
  const int c = threadIdx.x;       // 0..255 = head*64 + f
  const int head = c >> 6;
  const int f = c & 63;
  float wreg[FF];
#pragma unroll
  for (int k = 0; k < FF; ++k) wreg[k] = fc_w[k * HF + c];  // coalesced
  const float al = attn_l[c];
  const float ar = attn_r[c];
  for (int n = blockIdx.x; n < NN; n += gridDim.x) {
    const float* __restrict__ hr = h + (size_t)n * FF;
    float acc = 0.f;
#pragma unroll
    for (int k = 0; k < FF; ++k) acc = fmaf(hr[k], wreg[k], acc);
    featb[(size_t)n * HF + f * HH + head] = f32_to_bf16_rne(acc);
    float vl = acc * al, vr = acc * ar;
#pragma unroll
    for (int off = 32; off > 0; off >>= 1) {
      vl += __shfl_down(vl, off, 64);
      vr += __shfl_down(vr, off, 64);
    }
    if (f == 0) {
      el[n * HH + head] = vl;
      er[n * HH + head] = vr;
    }
  }
}

// ---------------- CSR build ------------------------------------------------
__global__ void k_hist(const int* __restrict__ dst, int* __restrict__ deg) {
  int e = blockIdx.x * blockDim.x + threadIdx.x;
  if (e < EE) atomicAdd(&deg[dst[e]], 1);
}

__global__ __launch_bounds__(1024) void k_scan(
    const int* __restrict__ deg, int* __restrict__ row_ptr,
    int* __restrict__ cursor) {
  __shared__ int sums[1024];
  const int t = threadIdx.x;
  const int chunk = (NN + 1023) / 1024;
  int lo = t * chunk, hi = lo + chunk;
  if (lo > NN) lo = NN;
  if (hi > NN) hi = NN;
  int s = 0;
  for (int i = lo; i < hi; ++i) s += deg[i];
  sums[t] = s;
  __syncthreads();
  for (int off = 1; off < 1024; off <<= 1) {
    int u = (t >= off) ? sums[t - off] : 0;
    __syncthreads();
    sums[t] += u;
    __syncthreads();
  }
  int run = sums[t] - s;
  for (int i = lo; i < hi; ++i) {
    row_ptr[i] = run;
    cursor[i] = run;
    run += deg[i];
  }
  if (t == 1023) row_ptr[NN] = sums[1023];
}

__global__ void k_scatter(const int* __restrict__ src,
                          const int* __restrict__ dst,
                          int* __restrict__ cursor, int* __restrict__ col) {
  int e = blockIdx.x * blockDim.x + threadIdx.x;
  if (e < EE) {
    int pos = atomicAdd(&cursor[dst[e]], 1);
    col[pos] = src[e];
  }
}

// ---------------- Kernel C: per-node softmax-weighted gather ---------------
// One wave per dst node. lane = f. feat row is bf16 [f][h]: ONE dwordx2 per
// lane fetches all 4 heads. Output rst as bf16 [n][h*64+f] for the MFMA GEMM.
__global__ __launch_bounds__(256) void k_gather(
    const unsigned short* __restrict__ featb, const float* __restrict__ el,
    const float* __restrict__ er, const int* __restrict__ row_ptr,
    const int* __restrict__ col, const float* __restrict__ gat_bias,
    unsigned short* __restrict__ rstb) {
  const int wave = threadIdx.x >> 6;
  const int lane = threadIdx.x & 63;
  const int gw = blockIdx.x * 4 + wave;
  const int stride = gridDim.x * 4;
  const float gb0 = gat_bias[lane], gb1 = gat_bias[64 + lane];
  const float gb2 = gat_bias[128 + lane], gb3 = gat_bias[192 + lane];
  for (int n = gw; n < NN; n += stride) {
    const int lo = row_ptr[n], hi = row_ptr[n + 1];
    const float4 erv = *(const float4*)(er + (size_t)n * 4);
    float a0 = 0.f, a1 = 0.f, a2 = 0.f, a3 = 0.f;
    float z0 = 0.f, z1 = 0.f, z2 = 0.f, z3 = 0.f;
    for (int idx = lo; idx < hi; ++idx) {
      const int s = col[idx];                     // wave-uniform
      const float4 elv = *(const float4*)(el + (size_t)s * 4);
      float e0 = elv.x + erv.x, e1 = elv.y + erv.y;
      float e2 = elv.z + erv.z, e3 = elv.w + erv.w;
      e0 = e0 > 0.f ? e0 : NEG_SLOPE * e0;
      e1 = e1 > 0.f ? e1 : NEG_SLOPE * e1;
      e2 = e2 > 0.f ? e2 : NEG_SLOPE * e2;
      e3 = e3 > 0.f ? e3 : NEG_SLOPE * e3;
      const float w0 = __expf(e0), w1 = __expf(e1);
      const float w2 = __expf(e2), w3 = __expf(e3);
      z0 += w0; z1 += w1; z2 += w2; z3 += w3;
      const uint2 d = *(const uint2*)(featb + (size_t)s * HF + lane * HH);
      const float f0 = __uint_as_float(d.x << 16);
      const float f1 = __uint_as_float(d.x & 0xFFFF0000u);
      const float f2 = __uint_as_float(d.y << 16);
      const float f3 = __uint_as_float(d.y & 0xFFFF0000u);
      a0 = fmaf(w0, f0, a0);
      a1 = fmaf(w1, f1, a1);
      a2 = fmaf(w2, f2, a2);
      a3 = fmaf(w3, f3, a3);
    }
    unsigned short* rp = rstb + (size_t)n * HF + lane;  // [n][h*64+f]
    rp[0]   = f32_to_bf16_rne((z0 > 0.f ? a0 / z0 : 0.f) + gb0);
    rp[64]  = f32_to_bf16_rne((z1 > 0.f ? a1 / z1 : 0.f) + gb1);
    rp[128] = f32_to_bf16_rne((z2 > 0.f ? a2 / z2 : 0.f) + gb2);
    rp[192] = f32_to_bf16_rne((z3 > 0.f ? a3 / z3 : 0.f) + gb3);
  }
}

// ---------------- pack out_w into MFMA B-fragment order --------------------
// B frag for 16x16x32: lane l holds B[k=32t+(l>>4)*8+j][n=16ct+(l&15)], j=0..7
// stored contiguously so k_out reads one ds_read_b128 per MFMA.
__global__ __launch_bounds__(256) void k_packw(const float* __restrict__ out_w,
                                               unsigned short* __restrict__ wpack) {
  for (int idx = threadIdx.x; idx < 4 * 8 * 64 * 8; idx += 256) {
    const int j = idx & 7;
    const int l = (idx >> 3) & 63;
    const int t = (idx >> 9) & 7;
    const int ct = idx >> 12;
    const int k = 32 * t + (l >> 4) * 8 + j;
    const int c = 16 * ct + (l & 15);
    wpack[idx] = f32_to_bf16_rne(out_w[k * FF + c]);
  }
}

// ---------------- Kernel D: x = rstb @ out_w + out_b ; LayerNorm (MFMA) ----
// One wave per 16-node tile (50000/16 = 3125 tiles). K=256 in 8 steps,
// 4 col-tiles of 16. A from global (16B/lane), B from LDS (ds_read_b128).
__global__ __launch_bounds__(256) void k_out(
    const unsigned short* __restrict__ rstb,
    const unsigned short* __restrict__ wpack,
    const float* __restrict__ out_b, const float* __restrict__ ln_g,
    const float* __restrict__ ln_b, float* __restrict__ out) {
  __shared__ unsigned short wlds[4 * 8 * 64 * 8];  // 32 KB
  {
    const uint4* src = (const uint4*)wpack;
    uint4* dstp = (uint4*)wlds;
    for (int i = threadIdx.x; i < 2048; i += 256) dstp[i] = src[i];
  }
  __syncthreads();
  const int wave = threadIdx.x >> 6;
  const int lane = threadIdx.x & 63;
  const int tile = blockIdx.x * 4 + wave;
  if (tile >= NN / 16) return;
  const int n0 = tile * 16;
  const int cl = lane & 15;        // C col within tile / A row within tile
  const int quad = lane >> 4;

  // A fragments: row = n0 + cl, k = 32t + quad*8 .. +8  (16B contiguous)
  const unsigned short* arow = rstb + (size_t)(n0 + cl) * HF + quad * 8;
  s8v a[8];
#pragma unroll
  for (int t = 0; t < 8; ++t) a[t] = *(const s8v*)(arow + 32 * t);

  f4v acc[4];
#pragma unroll
  for (int ct = 0; ct < 4; ++ct) {
    f4v z = {0.f, 0.f, 0.f, 0.f};
    acc[ct] = z;
#pragma unroll
    for (int t = 0; t < 8; ++t) {
      const s8v b = *(const s8v*)(wlds + ((ct * 8 + t) * 64 + lane) * 8);
      acc[ct] = __builtin_amdgcn_mfma_f32_16x16x32_bf16(a[t], b, acc[ct], 0, 0, 0);
    }
  }

  // epilogue: x = acc + out_b[col]; LayerNorm across 64 cols of each row.
  // C layout: col = 16ct + cl, row = quad*4 + r.
  float x[4][4];
  float s1[4], s2[4];
#pragma unroll
  for (int r = 0; r < 4; ++r) { s1[r] = 0.f; s2[r] = 0.f; }
#pragma unroll
  for (int ct = 0; ct < 4; ++ct) {
    const float ob = out_b[16 * ct + cl];
#pragma unroll
    for (int r = 0; r < 4; ++r) {
      const float v = acc[ct][r] + ob;
      x[ct][r] = v;
      s1[r] += v;
      s2[r] += v * v;
    }
  }
#pragma unroll
  for (int r = 0; r < 4; ++r) {
#pragma unroll
    for (int off = 1; off < 16; off <<= 1) {   // reduce across the 16-lane group
      s1[r] += __shfl_xor(s1[r], off, 64);
      s2[r] += __shfl_xor(s2[r], off, 64);
    }
  }
#pragma unroll
  for (int r = 0; r < 4; ++r) {
    const float mu = s1[r] * (1.f / 64.f);
    const float var = s2[r] * (1.f / 64.f) - mu * mu;
    const float inv = rsqrtf(var + LN_EPS);
    const int row = n0 + quad * 4 + r;
#pragma unroll
    for (int ct = 0; ct < 4; ++ct) {
      const int c = 16 * ct + cl;
      out[(size_t)row * FF + c] = (x[ct][r] - mu) * inv * ln_g[c] + ln_b[c];
    }
  }
}

// ---------------- launch ---------------------------------------------------
extern "C" void kernel_launch(void* const* d_in, const int* in_sizes, int n_in,
                              void* d_out, int out_size, void* d_ws,
                              size_t ws_size, hipStream_t stream) {
  const float* h_in   = (const float*)d_in[0];
  const int*   src    = (const int*)d_in[1];
  const int*   dst    = (const int*)d_in[2];
  const float* fc_w   = (const float*)d_in[3];
  const float* attn_l = (const float*)d_in[4];
  const float* attn_r = (const float*)d_in[5];
  const float* gbias  = (const float*)d_in[6];
  const float* out_w  = (const float*)d_in[7];
  const float* out_b  = (const float*)d_in[8];
  const float* ln_g   = (const float*)d_in[9];
  const float* ln_b   = (const float*)d_in[10];
  float* out = (float*)d_out;

  char* p = (char*)d_ws;
  auto alloc = [&](size_t bytes) {
    char* q = p;
    p += (bytes + 255) & ~(size_t)255;
    return q;
  };
  unsigned short* featb = (unsigned short*)alloc((size_t)NN * HF * 2);
  unsigned short* rstb  = (unsigned short*)alloc((size_t)NN * HF * 2);
  unsigned short* wpack = (unsigned short*)alloc((size_t)4 * 8 * 64 * 8 * 2);
  float* el      = (float*)alloc((size_t)NN * HH * 4);
  float* er      = (float*)alloc((size_t)NN * HH * 4);
  int*   deg     = (int*)alloc((size_t)NN * 4);
  int*   row_ptr = (int*)alloc((size_t)(NN + 1) * 4);
  int*   cursor  = (int*)alloc((size_t)NN * 4);
  int*   colidx  = (int*)alloc((size_t)EE * 4);

  hipMemsetAsync(deg, 0, (size_t)NN * sizeof(int), stream);
  k_feat<<<512, 256, 0, stream>>>(h_in, fc_w, attn_l, attn_r, featb, el, er);
  k_packw<<<1, 256, 0, stream>>>(out_w, wpack);
  k_hist<<<(EE + 255) / 256, 256, 0, stream>>>(dst, deg);
  k_scan<<<1, 1024, 0, stream>>>(deg, row_ptr, cursor);
  k_scatter<<<(EE + 255) / 256, 256, 0, stream>>>(src, dst, cursor, colidx);
  k_gather<<<2048, 256, 0, stream>>>(featb, el, er, row_ptr, colidx, gbias, rstb);
  k_out<<<(NN / 16 + 3) / 4, 256, 0, stream>>>(rstb, wpack, out_b, ln_g, ln_b, out);
}

// Round 4
// 363.880 us; speedup vs baseline: 1.6233x; 1.2871x over previous
//
#include <hip/hip_runtime.h>

#define NN 50000
#define EE 800000
#define FF 64
#define HH 4
#define HF 256          // H*F
#define NEG_SLOPE 0.2f
#define LN_EPS 1e-5f
#define NB1 196         // ceil(NN/256)

typedef __attribute__((ext_vector_type(8))) short s8v;    // 8 bf16 (4 VGPRs)
typedef __attribute__((ext_vector_type(4))) float f4v;    // 4 fp32 acc

__device__ __forceinline__ unsigned short f32_to_bf16_rne(float x) {
  unsigned int u = __float_as_uint(x);
  unsigned int r = u + 0x7FFFu + ((u >> 16) & 1u);
  return (unsigned short)(r >> 16);
}

// ---------------- Kernel A: feat = h @ fc_w ; el/er per (node, head) -------
__global__ __launch_bounds__(256) void k_feat(
    const float* __restrict__ h, const float* __restrict__ fc_w,
    const float* __restrict__ attn_l, const float* __restrict__ attn_r,
    unsigned short* __restrict__ featb, float* __restrict__ el,
    float* __restrict__ er) {
  const int c = threadIdx.x;       // 0..255 = head*64 + f
  const int head = c >> 6;
  const int f = c & 63;
  float wreg[FF];
#pragma unroll
  for (int k = 0; k < FF; ++k) wreg[k] = fc_w[k * HF + c];  // coalesced
  const float al = attn_l[c];
  const float ar = attn_r[c];
  for (int n = blockIdx.x; n < NN; n += gridDim.x) {
    const float* __restrict__ hr = h + (size_t)n * FF;
    float acc = 0.f;
#pragma unroll
    for (int k = 0; k < FF; ++k) acc = fmaf(hr[k], wreg[k], acc);
    featb[(size_t)n * HF + f * HH + head] = f32_to_bf16_rne(acc);
    float vl = acc * al, vr = acc * ar;
#pragma unroll
    for (int off = 32; off > 0; off >>= 1) {
      vl += __shfl_down(vl, off, 64);
      vr += __shfl_down(vr, off, 64);
    }
    if (f == 0) {
      el[n * HH + head] = vl;
      er[n * HH + head] = vr;
    }
  }
}

// ---------------- CSR build ------------------------------------------------
__global__ void k_hist(const int* __restrict__ dst, int* __restrict__ deg) {
  int e = blockIdx.x * blockDim.x + threadIdx.x;
  if (e < EE) atomicAdd(&deg[dst[e]], 1);
}

// phase 1: per-block sums of deg (coalesced, 1 elem/thread)
__global__ __launch_bounds__(256) void k_scan1(const int* __restrict__ deg,
                                               int* __restrict__ blocksum) {
  __shared__ int ws[4];
  const int i = blockIdx.x * 256 + threadIdx.x;
  const int lane = threadIdx.x & 63;
  const int wave = threadIdx.x >> 6;
  int v = (i < NN) ? deg[i] : 0;
#pragma unroll
  for (int off = 32; off > 0; off >>= 1) v += __shfl_down(v, off, 64);
  if (lane == 0) ws[wave] = v;
  __syncthreads();
  if (threadIdx.x == 0) blocksum[blockIdx.x] = ws[0] + ws[1] + ws[2] + ws[3];
}

// phase 2: exclusive scan of the NB1 block sums (single small block)
__global__ __launch_bounds__(256) void k_scan2(const int* __restrict__ blocksum,
                                               int* __restrict__ blockoff) {
  __shared__ int ws[4];
  const int t = threadIdx.x;
  const int lane = t & 63;
  const int wave = t >> 6;
  int v = (t < NB1) ? blocksum[t] : 0;
  int inc = v;
#pragma unroll
  for (int off = 1; off < 64; off <<= 1) {
    int u = __shfl_up(inc, off, 64);
    if (lane >= off) inc += u;
  }
  if (lane == 63) ws[wave] = inc;
  __syncthreads();
  int add = 0;
#pragma unroll
  for (int w = 0; w < 4; ++w) add += (w < wave) ? ws[w] : 0;
  if (t < NB1) blockoff[t] = add + inc - v;  // exclusive
}

// phase 3: intra-block exclusive scan + block offset -> row_ptr / cursor
__global__ __launch_bounds__(256) void k_scan3(const int* __restrict__ deg,
                                               const int* __restrict__ blockoff,
                                               int* __restrict__ row_ptr,
                                               int* __restrict__ cursor) {
  __shared__ int ws[4];
  const int i = blockIdx.x * 256 + threadIdx.x;
  const int lane = threadIdx.x & 63;
  const int wave = threadIdx.x >> 6;
  const int valid = (i < NN);
  int v = valid ? deg[i] : 0;
  int inc = v;
#pragma unroll
  for (int off = 1; off < 64; off <<= 1) {
    int u = __shfl_up(inc, off, 64);
    if (lane >= off) inc += u;
  }
  if (lane == 63) ws[wave] = inc;
  __syncthreads();
  int add = blockoff[blockIdx.x];
#pragma unroll
  for (int w = 0; w < 4; ++w) add += (w < wave) ? ws[w] : 0;
  const int run = add + inc - v;  // exclusive prefix
  if (valid) {
    row_ptr[i] = run;
    cursor[i] = run;
  }
  if (i == 0) row_ptr[NN] = EE;   // total edge count is a constant
}

__global__ void k_scatter(const int* __restrict__ src,
                          const int* __restrict__ dst,
                          int* __restrict__ cursor, int* __restrict__ col) {
  int e = blockIdx.x * blockDim.x + threadIdx.x;
  if (e < EE) {
    int pos = atomicAdd(&cursor[dst[e]], 1);
    col[pos] = src[e];
  }
}

// ---------------- Kernel C: per-node softmax-weighted gather ---------------
__global__ __launch_bounds__(256) void k_gather(
    const unsigned short* __restrict__ featb, const float* __restrict__ el,
    const float* __restrict__ er, const int* __restrict__ row_ptr,
    const int* __restrict__ col, const float* __restrict__ gat_bias,
    unsigned short* __restrict__ rstb) {
  const int wave = threadIdx.x >> 6;
  const int lane = threadIdx.x & 63;
  const int gw = blockIdx.x * 4 + wave;
  const int stride = gridDim.x * 4;
  const float gb0 = gat_bias[lane], gb1 = gat_bias[64 + lane];
  const float gb2 = gat_bias[128 + lane], gb3 = gat_bias[192 + lane];
  for (int n = gw; n < NN; n += stride) {
    const int lo = row_ptr[n], hi = row_ptr[n + 1];
    const float4 erv = *(const float4*)(er + (size_t)n * 4);
    float a0 = 0.f, a1 = 0.f, a2 = 0.f, a3 = 0.f;
    float z0 = 0.f, z1 = 0.f, z2 = 0.f, z3 = 0.f;
    for (int idx = lo; idx < hi; ++idx) {
      const int s = col[idx];                     // wave-uniform
      const float4 elv = *(const float4*)(el + (size_t)s * 4);
      float e0 = elv.x + erv.x, e1 = elv.y + erv.y;
      float e2 = elv.z + erv.z, e3 = elv.w + erv.w;
      e0 = e0 > 0.f ? e0 : NEG_SLOPE * e0;
      e1 = e1 > 0.f ? e1 : NEG_SLOPE * e1;
      e2 = e2 > 0.f ? e2 : NEG_SLOPE * e2;
      e3 = e3 > 0.f ? e3 : NEG_SLOPE * e3;
      const float w0 = __expf(e0), w1 = __expf(e1);
      const float w2 = __expf(e2), w3 = __expf(e3);
      z0 += w0; z1 += w1; z2 += w2; z3 += w3;
      const uint2 d = *(const uint2*)(featb + (size_t)s * HF + lane * HH);
      const float f0 = __uint_as_float(d.x << 16);
      const float f1 = __uint_as_float(d.x & 0xFFFF0000u);
      const float f2 = __uint_as_float(d.y << 16);
      const float f3 = __uint_as_float(d.y & 0xFFFF0000u);
      a0 = fmaf(w0, f0, a0);
      a1 = fmaf(w1, f1, a1);
      a2 = fmaf(w2, f2, a2);
      a3 = fmaf(w3, f3, a3);
    }
    unsigned short* rp = rstb + (size_t)n * HF + lane;  // [n][h*64+f]
    rp[0]   = f32_to_bf16_rne((z0 > 0.f ? a0 / z0 : 0.f) + gb0);
    rp[64]  = f32_to_bf16_rne((z1 > 0.f ? a1 / z1 : 0.f) + gb1);
    rp[128] = f32_to_bf16_rne((z2 > 0.f ? a2 / z2 : 0.f) + gb2);
    rp[192] = f32_to_bf16_rne((z3 > 0.f ? a3 / z3 : 0.f) + gb3);
  }
}

// ---------------- pack out_w into MFMA B-fragment order --------------------
__global__ __launch_bounds__(256) void k_packw(const float* __restrict__ out_w,
                                               unsigned short* __restrict__ wpack) {
  for (int idx = threadIdx.x; idx < 4 * 8 * 64 * 8; idx += 256) {
    const int j = idx & 7;
    const int l = (idx >> 3) & 63;
    const int t = (idx >> 9) & 7;
    const int ct = idx >> 12;
    const int k = 32 * t + (l >> 4) * 8 + j;
    const int c = 16 * ct + (l & 15);
    wpack[idx] = f32_to_bf16_rne(out_w[k * FF + c]);
  }
}

// ---------------- Kernel D: x = rstb @ out_w + out_b ; LayerNorm (MFMA) ----
__global__ __launch_bounds__(256) void k_out(
    const unsigned short* __restrict__ rstb,
    const unsigned short* __restrict__ wpack,
    const float* __restrict__ out_b, const float* __restrict__ ln_g,
    const float* __restrict__ ln_b, float* __restrict__ out) {
  __shared__ unsigned short wlds[4 * 8 * 64 * 8];  // 32 KB
  {
    const uint4* src = (const uint4*)wpack;
    uint4* dstp = (uint4*)wlds;
    for (int i = threadIdx.x; i < 2048; i += 256) dstp[i] = src[i];
  }
  __syncthreads();
  const int wave = threadIdx.x >> 6;
  const int lane = threadIdx.x & 63;
  const int tile = blockIdx.x * 4 + wave;
  if (tile >= NN / 16) return;
  const int n0 = tile * 16;
  const int cl = lane & 15;
  const int quad = lane >> 4;

  const unsigned short* arow = rstb + (size_t)(n0 + cl) * HF + quad * 8;
  s8v a[8];
#pragma unroll
  for (int t = 0; t < 8; ++t) a[t] = *(const s8v*)(arow + 32 * t);

  f4v acc[4];
#pragma unroll
  for (int ct = 0; ct < 4; ++ct) {
    f4v z = {0.f, 0.f, 0.f, 0.f};
    acc[ct] = z;
#pragma unroll
    for (int t = 0; t < 8; ++t) {
      const s8v b = *(const s8v*)(wlds + ((ct * 8 + t) * 64 + lane) * 8);
      acc[ct] = __builtin_amdgcn_mfma_f32_16x16x32_bf16(a[t], b, acc[ct], 0, 0, 0);
    }
  }

  float x[4][4];
  float s1[4], s2[4];
#pragma unroll
  for (int r = 0; r < 4; ++r) { s1[r] = 0.f; s2[r] = 0.f; }
#pragma unroll
  for (int ct = 0; ct < 4; ++ct) {
    const float ob = out_b[16 * ct + cl];
#pragma unroll
    for (int r = 0; r < 4; ++r) {
      const float v = acc[ct][r] + ob;
      x[ct][r] = v;
      s1[r] += v;
      s2[r] += v * v;
    }
  }
#pragma unroll
  for (int r = 0; r < 4; ++r) {
#pragma unroll
    for (int off = 1; off < 16; off <<= 1) {
      s1[r] += __shfl_xor(s1[r], off, 64);
      s2[r] += __shfl_xor(s2[r], off, 64);
    }
  }
#pragma unroll
  for (int r = 0; r < 4; ++r) {
    const float mu = s1[r] * (1.f / 64.f);
    const float var = s2[r] * (1.f / 64.f) - mu * mu;
    const float inv = rsqrtf(var + LN_EPS);
    const int row = n0 + quad * 4 + r;
#pragma unroll
    for (int ct = 0; ct < 4; ++ct) {
      const int c = 16 * ct + cl;
      out[(size_t)row * FF + c] = (x[ct][r] - mu) * inv * ln_g[c] + ln_b[c];
    }
  }
}

// ---------------- launch ---------------------------------------------------
extern "C" void kernel_launch(void* const* d_in, const int* in_sizes, int n_in,
                              void* d_out, int out_size, void* d_ws,
                              size_t ws_size, hipStream_t stream) {
  const float* h_in   = (const float*)d_in[0];
  const int*   src    = (const int*)d_in[1];
  const int*   dst    = (const int*)d_in[2];
  const float* fc_w   = (const float*)d_in[3];
  const float* attn_l = (const float*)d_in[4];
  const float* attn_r = (const float*)d_in[5];
  const float* gbias  = (const float*)d_in[6];
  const float* out_w  = (const float*)d_in[7];
  const float* out_b  = (const float*)d_in[8];
  const float* ln_g   = (const float*)d_in[9];
  const float* ln_b   = (const float*)d_in[10];
  float* out = (float*)d_out;

  char* p = (char*)d_ws;
  auto alloc = [&](size_t bytes) {
    char* q = p;
    p += (bytes + 255) & ~(size_t)255;
    return q;
  };
  unsigned short* featb = (unsigned short*)alloc((size_t)NN * HF * 2);
  unsigned short* rstb  = (unsigned short*)alloc((size_t)NN * HF * 2);
  unsigned short* wpack = (unsigned short*)alloc((size_t)4 * 8 * 64 * 8 * 2);
  float* el      = (float*)alloc((size_t)NN * HH * 4);
  float* er      = (float*)alloc((size_t)NN * HH * 4);
  int*   deg     = (int*)alloc((size_t)NN * 4);
  int*   row_ptr = (int*)alloc((size_t)(NN + 1) * 4);
  int*   cursor  = (int*)alloc((size_t)NN * 4);
  int*   colidx  = (int*)alloc((size_t)EE * 4);
  int*   blocksum= (int*)alloc((size_t)NB1 * 4);
  int*   blockoff= (int*)alloc((size_t)NB1 * 4);

  hipMemsetAsync(deg, 0, (size_t)NN * sizeof(int), stream);
  k_feat<<<512, 256, 0, stream>>>(h_in, fc_w, attn_l, attn_r, featb, el, er);
  k_packw<<<1, 256, 0, stream>>>(out_w, wpack);
  k_hist<<<(EE + 255) / 256, 256, 0, stream>>>(dst, deg);
  k_scan1<<<NB1, 256, 0, stream>>>(deg, blocksum);
  k_scan2<<<1, 256, 0, stream>>>(blocksum, blockoff);
  k_scan3<<<NB1, 256, 0, stream>>>(deg, blockoff, row_ptr, cursor);
  k_scatter<<<(EE + 255) / 256, 256, 0, stream>>>(src, dst, cursor, colidx);
  k_gather<<<2048, 256, 0, stream>>>(featb, el, er, row_ptr, colidx, gbias, rstb);
  k_out<<<(NN / 16 + 3) / 4, 256, 0, stream>>>(rstb, wpack, out_b, ln_g, ln_b, out);
}

// Round 6
// 326.511 us; speedup vs baseline: 1.8091x; 1.1144x over previous
//
#include <hip/hip_runtime.h>

#define NN 50000
#define EE 800000
#define FF 64
#define HH 4
#define HF 256          // H*F
#define NEG_SLOPE 0.2f
#define LN_EPS 1e-5f
#define NB1 196         // ceil(NN/256)
#define WPACK_N (4 * 8 * 64 * 8)   // 16384 bf16 elements

typedef __attribute__((ext_vector_type(8))) short s8v;    // 8 bf16 (4 VGPRs)
typedef __attribute__((ext_vector_type(4))) float f4v;    // 4 fp32 acc

__device__ __forceinline__ unsigned short f32_to_bf16_rne(float x) {
  unsigned int u = __float_as_uint(x);
  unsigned int r = u + 0x7FFFu + ((u >> 16) & 1u);
  return (unsigned short)(r >> 16);
}

// ---------------- Kernel A: feat = h @ fc_w ; el/er per (node, head) -------
__global__ __launch_bounds__(256) void k_feat(
    const float* __restrict__ h, const float* __restrict__ fc_w,
    const float* __restrict__ attn_l, const float* __restrict__ attn_r,
    unsigned short* __restrict__ featb, float* __restrict__ el,
    float* __restrict__ er) {
  const int c = threadIdx.x;       // 0..255 = head*64 + f
  const int head = c >> 6;
  const int f = c & 63;
  float wreg[FF];
#pragma unroll
  for (int k = 0; k < FF; ++k) wreg[k] = fc_w[k * HF + c];  // coalesced
  const float al = attn_l[c];
  const float ar = attn_r[c];
  for (int n = blockIdx.x; n < NN; n += gridDim.x) {
    const float* __restrict__ hr = h + (size_t)n * FF;
    float acc = 0.f;
#pragma unroll
    for (int k = 0; k < FF; ++k) acc = fmaf(hr[k], wreg[k], acc);
    featb[(size_t)n * HF + f * HH + head] = f32_to_bf16_rne(acc);
    float vl = acc * al, vr = acc * ar;
#pragma unroll
    for (int off = 32; off > 0; off >>= 1) {
      vl += __shfl_down(vl, off, 64);
      vr += __shfl_down(vr, off, 64);
    }
    if (f == 0) {
      el[n * HH + head] = vl;
      er[n * HH + head] = vr;
    }
  }
}

// ---------------- CSR build ------------------------------------------------
__global__ void k_hist(const int* __restrict__ dst, int* __restrict__ deg) {
  int e = blockIdx.x * blockDim.x + threadIdx.x;
  if (e < EE) atomicAdd(&deg[dst[e]], 1);
}

__global__ __launch_bounds__(256) void k_scan1(const int* __restrict__ deg,
                                               int* __restrict__ blocksum) {
  __shared__ int ws[4];
  const int i = blockIdx.x * 256 + threadIdx.x;
  const int lane = threadIdx.x & 63;
  const int wave = threadIdx.x >> 6;
  int v = (i < NN) ? deg[i] : 0;
#pragma unroll
  for (int off = 32; off > 0; off >>= 1) v += __shfl_down(v, off, 64);
  if (lane == 0) ws[wave] = v;
  __syncthreads();
  if (threadIdx.x == 0) blocksum[blockIdx.x] = ws[0] + ws[1] + ws[2] + ws[3];
}

__global__ __launch_bounds__(256) void k_scan2(const int* __restrict__ blocksum,
                                               int* __restrict__ blockoff) {
  __shared__ int ws[4];
  const int t = threadIdx.x;
  const int lane = t & 63;
  const int wave = t >> 6;
  int v = (t < NB1) ? blocksum[t] : 0;
  int inc = v;
#pragma unroll
  for (int off = 1; off < 64; off <<= 1) {
    int u = __shfl_up(inc, off, 64);
    if (lane >= off) inc += u;
  }
  if (lane == 63) ws[wave] = inc;
  __syncthreads();
  int add = 0;
#pragma unroll
  for (int w = 0; w < 4; ++w) add += (w < wave) ? ws[w] : 0;
  if (t < NB1) blockoff[t] = add + inc - v;  // exclusive
}

__global__ __launch_bounds__(256) void k_scan3(const int* __restrict__ deg,
                                               const int* __restrict__ blockoff,
                                               int* __restrict__ row_ptr,
                                               int* __restrict__ cursor) {
  __shared__ int ws[4];
  const int i = blockIdx.x * 256 + threadIdx.x;
  const int lane = threadIdx.x & 63;
  const int wave = threadIdx.x >> 6;
  const int valid = (i < NN);
  int v = valid ? deg[i] : 0;
  int inc = v;
#pragma unroll
  for (int off = 1; off < 64; off <<= 1) {
    int u = __shfl_up(inc, off, 64);
    if (lane >= off) inc += u;
  }
  if (lane == 63) ws[wave] = inc;
  __syncthreads();
  int add = blockoff[blockIdx.x];
#pragma unroll
  for (int w = 0; w < 4; ++w) add += (w < wave) ? ws[w] : 0;
  const int run = add + inc - v;  // exclusive prefix
  if (valid) {
    row_ptr[i] = run;
    cursor[i] = run;
  }
  if (i == 0) row_ptr[NN] = EE;
}

__global__ void k_scatter(const int* __restrict__ src,
                          const int* __restrict__ dst,
                          int* __restrict__ cursor, int* __restrict__ col) {
  int e = blockIdx.x * blockDim.x + threadIdx.x;
  if (e < EE) {
    int pos = atomicAdd(&cursor[dst[e]], 1);
    col[pos] = src[e];
  }
}

// ---------------- Kernel C: per-node softmax-weighted gather ---------------
// One wave per dst node. Per 64-edge chunk: phase A = lane-parallel weight
// computation (lane = edge); phase B = per-edge accumulation with weights
// broadcast from wave-private LDS (uniform address -> LDS broadcast).
__global__ __launch_bounds__(256) void k_gather(
    const unsigned short* __restrict__ featb, const float* __restrict__ el,
    const float* __restrict__ er, const int* __restrict__ row_ptr,
    const int* __restrict__ col, const float* __restrict__ gat_bias,
    unsigned short* __restrict__ rstb) {
  __shared__ int    slds[4][64];
  __shared__ float4 wldsv[4][64];
  const int wave = threadIdx.x >> 6;
  const int lane = threadIdx.x & 63;
  const int gw = blockIdx.x * 4 + wave;
  const int stride = gridDim.x * 4;
  const float gb0 = gat_bias[lane], gb1 = gat_bias[64 + lane];
  const float gb2 = gat_bias[128 + lane], gb3 = gat_bias[192 + lane];
  for (int n = gw; n < NN; n += stride) {
    const int lo = row_ptr[n], hi = row_ptr[n + 1];
    const float4 erv = *(const float4*)(er + (size_t)n * 4);
    float a0 = 0.f, a1 = 0.f, a2 = 0.f, a3 = 0.f;
    float z0 = 0.f, z1 = 0.f, z2 = 0.f, z3 = 0.f;
    for (int base = lo; base < hi; base += 64) {
      const int m = (hi - base < 64) ? (hi - base) : 64;
      // ---- phase A: lane-parallel weight computation (lane = edge) ----
      float w0 = 0.f, w1 = 0.f, w2 = 0.f, w3 = 0.f;
      int s = 0;
      if (lane < m) {
        s = col[base + lane];                       // coalesced
        const float4 elv = *(const float4*)(el + (size_t)s * 4);
        float e0 = elv.x + erv.x, e1 = elv.y + erv.y;
        float e2 = elv.z + erv.z, e3 = elv.w + erv.w;
        e0 = e0 > 0.f ? e0 : NEG_SLOPE * e0;
        e1 = e1 > 0.f ? e1 : NEG_SLOPE * e1;
        e2 = e2 > 0.f ? e2 : NEG_SLOPE * e2;
        e3 = e3 > 0.f ? e3 : NEG_SLOPE * e3;
        w0 = __expf(e0); w1 = __expf(e1);
        w2 = __expf(e2); w3 = __expf(e3);
      }
      z0 += w0; z1 += w1; z2 += w2; z3 += w3;
      slds[wave][lane] = s;
      wldsv[wave][lane] = make_float4(w0, w1, w2, w3);
      // same-wave LDS round-trip: program order + lgkmcnt waits suffice
      // ---- phase B: accumulate edges; weights broadcast from LDS ----
      for (int e = 0; e < m; ++e) {
        const int se = slds[wave][e];               // uniform -> broadcast
        const float4 wv = wldsv[wave][e];
        const uint2 d = *(const uint2*)(featb + (size_t)se * HF + lane * HH);
        const float f0 = __uint_as_float(d.x << 16);
        const float f1 = __uint_as_float(d.x & 0xFFFF0000u);
        const float f2 = __uint_as_float(d.y << 16);
        const float f3 = __uint_as_float(d.y & 0xFFFF0000u);
        a0 = fmaf(wv.x, f0, a0);
        a1 = fmaf(wv.y, f1, a1);
        a2 = fmaf(wv.z, f2, a2);
        a3 = fmaf(wv.w, f3, a3);
      }
    }
    // wave-reduce z (per-lane partials -> all lanes)
#pragma unroll
    for (int off = 1; off < 64; off <<= 1) {
      z0 += __shfl_xor(z0, off, 64);
      z1 += __shfl_xor(z1, off, 64);
      z2 += __shfl_xor(z2, off, 64);
      z3 += __shfl_xor(z3, off, 64);
    }
    unsigned short* rp = rstb + (size_t)n * HF + lane;  // [n][h*64+f]
    rp[0]   = f32_to_bf16_rne((z0 > 0.f ? a0 / z0 : 0.f) + gb0);
    rp[64]  = f32_to_bf16_rne((z1 > 0.f ? a1 / z1 : 0.f) + gb1);
    rp[128] = f32_to_bf16_rne((z2 > 0.f ? a2 / z2 : 0.f) + gb2);
    rp[192] = f32_to_bf16_rne((z3 > 0.f ? a3 / z3 : 0.f) + gb3);
  }
}

// ---------------- pack out_w into MFMA B-fragment order --------------------
// WPACK_N = 16384 elements; 64 blocks x 256 threads = exactly one per elem.
__global__ __launch_bounds__(256) void k_packw(const float* __restrict__ out_w,
                                               unsigned short* __restrict__ wpack) {
  const int idx = blockIdx.x * 256 + threadIdx.x;
  if (idx >= WPACK_N) return;      // guard (grid sized to match, belt+braces)
  const int j = idx & 7;
  const int l = (idx >> 3) & 63;
  const int t = (idx >> 9) & 7;
  const int ct = idx >> 12;
  const int k = 32 * t + (l >> 4) * 8 + j;
  const int c = 16 * ct + (l & 15);
  wpack[idx] = f32_to_bf16_rne(out_w[k * FF + c]);
}

// ---------------- Kernel D: x = rstb @ out_w + out_b ; LayerNorm (MFMA) ----
__global__ __launch_bounds__(256) void k_out(
    const unsigned short* __restrict__ rstb,
    const unsigned short* __restrict__ wpack,
    const float* __restrict__ out_b, const float* __restrict__ ln_g,
    const float* __restrict__ ln_b, float* __restrict__ out) {
  __shared__ unsigned short wlds[WPACK_N];  // 32 KB
  {
    const uint4* src = (const uint4*)wpack;
    uint4* dstp = (uint4*)wlds;
    for (int i = threadIdx.x; i < 2048; i += 256) dstp[i] = src[i];
  }
  __syncthreads();
  const int wave = threadIdx.x >> 6;
  const int lane = threadIdx.x & 63;
  const int tile = blockIdx.x * 4 + wave;
  if (tile >= NN / 16) return;
  const int n0 = tile * 16;
  const int cl = lane & 15;
  const int quad = lane >> 4;

  const unsigned short* arow = rstb + (size_t)(n0 + cl) * HF + quad * 8;
  s8v a[8];
#pragma unroll
  for (int t = 0; t < 8; ++t) a[t] = *(const s8v*)(arow + 32 * t);

  f4v acc[4];
#pragma unroll
  for (int ct = 0; ct < 4; ++ct) {
    f4v z = {0.f, 0.f, 0.f, 0.f};
    acc[ct] = z;
#pragma unroll
    for (int t = 0; t < 8; ++t) {
      const s8v b = *(const s8v*)(wlds + ((ct * 8 + t) * 64 + lane) * 8);
      acc[ct] = __builtin_amdgcn_mfma_f32_16x16x32_bf16(a[t], b, acc[ct], 0, 0, 0);
    }
  }

  float x[4][4];
  float s1[4], s2[4];
#pragma unroll
  for (int r = 0; r < 4; ++r) { s1[r] = 0.f; s2[r] = 0.f; }
#pragma unroll
  for (int ct = 0; ct < 4; ++ct) {
    const float ob = out_b[16 * ct + cl];
#pragma unroll
    for (int r = 0; r < 4; ++r) {
      const float v = acc[ct][r] + ob;
      x[ct][r] = v;
      s1[r] += v;
      s2[r] += v * v;
    }
  }
#pragma unroll
  for (int r = 0; r < 4; ++r) {
#pragma unroll
    for (int off = 1; off < 16; off <<= 1) {
      s1[r] += __shfl_xor(s1[r], off, 64);
      s2[r] += __shfl_xor(s2[r], off, 64);
    }
  }
#pragma unroll
  for (int r = 0; r < 4; ++r) {
    const float mu = s1[r] * (1.f / 64.f);
    const float var = s2[r] * (1.f / 64.f) - mu * mu;
    const float inv = rsqrtf(var + LN_EPS);
    const int row = n0 + quad * 4 + r;
#pragma unroll
    for (int ct = 0; ct < 4; ++ct) {
      const int c = 16 * ct + cl;
      out[(size_t)row * FF + c] = (x[ct][r] - mu) * inv * ln_g[c] + ln_b[c];
    }
  }
}

// ---------------- launch ---------------------------------------------------
extern "C" void kernel_launch(void* const* d_in, const int* in_sizes, int n_in,
                              void* d_out, int out_size, void* d_ws,
                              size_t ws_size, hipStream_t stream) {
  const float* h_in   = (const float*)d_in[0];
  const int*   src    = (const int*)d_in[1];
  const int*   dst    = (const int*)d_in[2];
  const float* fc_w   = (const float*)d_in[3];
  const float* attn_l = (const float*)d_in[4];
  const float* attn_r = (const float*)d_in[5];
  const float* gbias  = (const float*)d_in[6];
  const float* out_w  = (const float*)d_in[7];
  const float* out_b  = (const float*)d_in[8];
  const float* ln_g   = (const float*)d_in[9];
  const float* ln_b   = (const float*)d_in[10];
  float* out = (float*)d_out;

  char* p = (char*)d_ws;
  auto alloc = [&](size_t bytes) {
    char* q = p;
    p += (bytes + 255) & ~(size_t)255;
    return q;
  };
  unsigned short* featb = (unsigned short*)alloc((size_t)NN * HF * 2);
  unsigned short* rstb  = (unsigned short*)alloc((size_t)NN * HF * 2);
  unsigned short* wpack = (unsigned short*)alloc((size_t)WPACK_N * 2);
  float* el      = (float*)alloc((size_t)NN * HH * 4);
  float* er      = (float*)alloc((size_t)NN * HH * 4);
  int*   deg     = (int*)alloc((size_t)NN * 4);
  int*   row_ptr = (int*)alloc((size_t)(NN + 1) * 4);
  int*   cursor  = (int*)alloc((size_t)NN * 4);
  int*   colidx  = (int*)alloc((size_t)EE * 4);
  int*   blocksum= (int*)alloc((size_t)NB1 * 4);
  int*   blockoff= (int*)alloc((size_t)NB1 * 4);

  hipMemsetAsync(deg, 0, (size_t)NN * sizeof(int), stream);
  k_feat<<<512, 256, 0, stream>>>(h_in, fc_w, attn_l, attn_r, featb, el, er);
  k_packw<<<WPACK_N / 256, 256, 0, stream>>>(out_w, wpack);
  k_hist<<<(EE + 255) / 256, 256, 0, stream>>>(dst, deg);
  k_scan1<<<NB1, 256, 0, stream>>>(deg, blocksum);
  k_scan2<<<1, 256, 0, stream>>>(blocksum, blockoff);
  k_scan3<<<NB1, 256, 0, stream>>>(deg, blockoff, row_ptr, cursor);
  k_scatter<<<(EE + 255) / 256, 256, 0, stream>>>(src, dst, cursor, colidx);
  k_gather<<<2048, 256, 0, stream>>>(featb, el, er, row_ptr, colidx, gbias, rstb);
  k_out<<<(NN / 16 + 3) / 4, 256, 0, stream>>>(rstb, wpack, out_b, ln_g, ln_b, out);
}

// Round 7
// 276.542 us; speedup vs baseline: 2.1360x; 1.1807x over previous
//
#include <hip/hip_runtime.h>

#define NN 50000
#define EE 800000
#define FF 64
#define HH 4
#define HF 256          // H*F
#define NEG_SLOPE 0.2f
#define LN_EPS 1e-5f
#define NB1 196         // ceil(NN/256)
#define WPACK_N (4 * 8 * 64 * 8)   // 16384 bf16 elements (k_out B-frags)
#define WPACKA_N (16 * 2 * 64 * 8) // 16384 bf16 elements (k_feat B-frags)
#define NTILE (NN / 16)            // 3125 node tiles

typedef __attribute__((ext_vector_type(8))) short s8v;    // 8 bf16 (4 VGPRs)
typedef __attribute__((ext_vector_type(4))) float f4v;    // 4 fp32 acc

__device__ __forceinline__ unsigned short f32_to_bf16_rne(float x) {
  unsigned int u = __float_as_uint(x);
  unsigned int r = u + 0x7FFFu + ((u >> 16) & 1u);
  return (unsigned short)(r >> 16);
}

// ---------------- pack fc_w into MFMA B-fragment order (K=64) --------------
// B frag: lane l holds B[k=32t+(l>>4)*8+j][c=16ct+(l&15)], j=0..7 contiguous.
// ct=0..15 (16 col-tiles of 256 cols), t=0..1 (2 k-steps of K=64).
__global__ __launch_bounds__(256) void k_packwA(const float* __restrict__ fc_w,
                                                unsigned short* __restrict__ wpackA) {
  const int idx = blockIdx.x * 256 + threadIdx.x;
  if (idx >= WPACKA_N) return;
  const int j = idx & 7;
  const int l = (idx >> 3) & 63;
  const int t = (idx >> 9) & 1;
  const int ct = idx >> 10;
  const int k = 32 * t + (l >> 4) * 8 + j;
  const int c = 16 * ct + (l & 15);
  wpackA[idx] = f32_to_bf16_rne(fc_w[k * HF + c]);
}

// ---------------- Kernel A (MFMA): feat = h @ fc_w ; el/er -----------------
// One wave per 16-node tile. A from global fp32 h (convert to bf16 in-reg),
// B from LDS. Epilogue: featb [n][f*4+head] packed 4 heads per uint2 store;
// el/er via per-head FMA partials + 16-lane shfl_xor reduction.
__global__ __launch_bounds__(256) void k_feat(
    const float* __restrict__ h, const unsigned short* __restrict__ wpackA,
    const float* __restrict__ attn_l, const float* __restrict__ attn_r,
    unsigned short* __restrict__ featb, float* __restrict__ el,
    float* __restrict__ er) {
  __shared__ unsigned short wlds[WPACKA_N];  // 32 KB
  {
    const uint4* s = (const uint4*)wpackA;
    uint4* d = (uint4*)wlds;
    for (int i = threadIdx.x; i < 2048; i += 256) d[i] = s[i];
  }
  __syncthreads();
  const int wave = threadIdx.x >> 6;
  const int lane = threadIdx.x & 63;
  const int tile = blockIdx.x * 4 + wave;
  if (tile >= NTILE) return;
  const int n0 = tile * 16;
  const int cl = lane & 15;
  const int quad = lane >> 4;

  // attn per lane: al[ct] pairs with C col c = 16ct + cl
  float al[16], ar[16];
#pragma unroll
  for (int ct = 0; ct < 16; ++ct) {
    al[ct] = attn_l[16 * ct + cl];
    ar[ct] = attn_r[16 * ct + cl];
  }

  // A frags: row n0+cl, k = 32t + quad*8 + j (8 fp32 -> 8 bf16)
  s8v a[2];
#pragma unroll
  for (int t = 0; t < 2; ++t) {
    const float* hp = h + (size_t)(n0 + cl) * FF + 32 * t + quad * 8;
    float hv[8];
    *(float4*)hv = *(const float4*)hp;
    *(float4*)(hv + 4) = *(const float4*)(hp + 4);
    s8v av;
#pragma unroll
    for (int i = 0; i < 8; ++i) av[i] = (short)f32_to_bf16_rne(hv[i]);
    a[t] = av;
  }

  f4v acc[16];
#pragma unroll
  for (int ct = 0; ct < 16; ++ct) {
    f4v z = {0.f, 0.f, 0.f, 0.f};
    acc[ct] = z;
#pragma unroll
    for (int t = 0; t < 2; ++t) {
      const s8v b = *(const s8v*)(wlds + ((ct * 2 + t) * 64 + lane) * 8);
      acc[ct] = __builtin_amdgcn_mfma_f32_16x16x32_bf16(a[t], b, acc[ct], 0, 0, 0);
    }
  }

  // Epilogue. C: col = 16ct+cl, row = quad*4+r. head = ct>>2, f = 16(ct&3)+cl.
  // For group g=ct&3: heads {0..3} from ct={g,g+4,g+8,g+12} share f=16g+cl ->
  // one uint2 (4 bf16) store at featb[n][(16g+cl)*4].
#pragma unroll
  for (int r = 0; r < 4; ++r) {
    const int n = n0 + quad * 4 + r;
    float pl[4] = {0.f, 0.f, 0.f, 0.f};
    float pr[4] = {0.f, 0.f, 0.f, 0.f};
#pragma unroll
    for (int g = 0; g < 4; ++g) {
      const float x0 = acc[g][r];       // head 0
      const float x1 = acc[g + 4][r];   // head 1
      const float x2 = acc[g + 8][r];   // head 2
      const float x3 = acc[g + 12][r];  // head 3
      uint2 pk;
      pk.x = (unsigned)f32_to_bf16_rne(x0) | ((unsigned)f32_to_bf16_rne(x1) << 16);
      pk.y = (unsigned)f32_to_bf16_rne(x2) | ((unsigned)f32_to_bf16_rne(x3) << 16);
      *(uint2*)(featb + (size_t)n * HF + (16 * g + cl) * 4) = pk;
      pl[0] = fmaf(x0, al[g], pl[0]);      pr[0] = fmaf(x0, ar[g], pr[0]);
      pl[1] = fmaf(x1, al[g + 4], pl[1]);  pr[1] = fmaf(x1, ar[g + 4], pr[1]);
      pl[2] = fmaf(x2, al[g + 8], pl[2]);  pr[2] = fmaf(x2, ar[g + 8], pr[2]);
      pl[3] = fmaf(x3, al[g + 12], pl[3]); pr[3] = fmaf(x3, ar[g + 12], pr[3]);
    }
#pragma unroll
    for (int off = 1; off < 16; off <<= 1) {
#pragma unroll
      for (int hh = 0; hh < 4; ++hh) {
        pl[hh] += __shfl_xor(pl[hh], off, 64);
        pr[hh] += __shfl_xor(pr[hh], off, 64);
      }
    }
    if (cl == 0) {
      *(float4*)(el + (size_t)n * 4) = make_float4(pl[0], pl[1], pl[2], pl[3]);
      *(float4*)(er + (size_t)n * 4) = make_float4(pr[0], pr[1], pr[2], pr[3]);
    }
  }
}

// ---------------- CSR build ------------------------------------------------
__global__ void k_hist(const int* __restrict__ dst, int* __restrict__ deg) {
  int e = blockIdx.x * blockDim.x + threadIdx.x;
  if (e < EE) atomicAdd(&deg[dst[e]], 1);
}

__global__ __launch_bounds__(256) void k_scan1(const int* __restrict__ deg,
                                               int* __restrict__ blocksum) {
  __shared__ int ws[4];
  const int i = blockIdx.x * 256 + threadIdx.x;
  const int lane = threadIdx.x & 63;
  const int wave = threadIdx.x >> 6;
  int v = (i < NN) ? deg[i] : 0;
#pragma unroll
  for (int off = 32; off > 0; off >>= 1) v += __shfl_down(v, off, 64);
  if (lane == 0) ws[wave] = v;
  __syncthreads();
  if (threadIdx.x == 0) blocksum[blockIdx.x] = ws[0] + ws[1] + ws[2] + ws[3];
}

__global__ __launch_bounds__(256) void k_scan2(const int* __restrict__ blocksum,
                                               int* __restrict__ blockoff) {
  __shared__ int ws[4];
  const int t = threadIdx.x;
  const int lane = t & 63;
  const int wave = t >> 6;
  int v = (t < NB1) ? blocksum[t] : 0;
  int inc = v;
#pragma unroll
  for (int off = 1; off < 64; off <<= 1) {
    int u = __shfl_up(inc, off, 64);
    if (lane >= off) inc += u;
  }
  if (lane == 63) ws[wave] = inc;
  __syncthreads();
  int add = 0;
#pragma unroll
  for (int w = 0; w < 4; ++w) add += (w < wave) ? ws[w] : 0;
  if (t < NB1) blockoff[t] = add + inc - v;  // exclusive
}

__global__ __launch_bounds__(256) void k_scan3(const int* __restrict__ deg,
                                               const int* __restrict__ blockoff,
                                               int* __restrict__ row_ptr,
                                               int* __restrict__ cursor) {
  __shared__ int ws[4];
  const int i = blockIdx.x * 256 + threadIdx.x;
  const int lane = threadIdx.x & 63;
  const int wave = threadIdx.x >> 6;
  const int valid = (i < NN);
  int v = valid ? deg[i] : 0;
  int inc = v;
#pragma unroll
  for (int off = 1; off < 64; off <<= 1) {
    int u = __shfl_up(inc, off, 64);
    if (lane >= off) inc += u;
  }
  if (lane == 63) ws[wave] = inc;
  __syncthreads();
  int add = blockoff[blockIdx.x];
#pragma unroll
  for (int w = 0; w < 4; ++w) add += (w < wave) ? ws[w] : 0;
  const int run = add + inc - v;  // exclusive prefix
  if (valid) {
    row_ptr[i] = run;
    cursor[i] = run;
  }
  if (i == 0) row_ptr[NN] = EE;
}

__global__ void k_scatter(const int* __restrict__ src,
                          const int* __restrict__ dst,
                          int* __restrict__ cursor, int* __restrict__ col) {
  int e = blockIdx.x * blockDim.x + threadIdx.x;
  if (e < EE) {
    int pos = atomicAdd(&cursor[dst[e]], 1);
    col[pos] = src[e];
  }
}

// ---------------- Kernel C: per-node softmax-weighted gather ---------------
__global__ __launch_bounds__(256) void k_gather(
    const unsigned short* __restrict__ featb, const float* __restrict__ el,
    const float* __restrict__ er, const int* __restrict__ row_ptr,
    const int* __restrict__ col, const float* __restrict__ gat_bias,
    unsigned short* __restrict__ rstb) {
  __shared__ int    slds[4][64];
  __shared__ float4 wldsv[4][64];
  const int wave = threadIdx.x >> 6;
  const int lane = threadIdx.x & 63;
  const int gw = blockIdx.x * 4 + wave;
  const int stride = gridDim.x * 4;
  const float gb0 = gat_bias[lane], gb1 = gat_bias[64 + lane];
  const float gb2 = gat_bias[128 + lane], gb3 = gat_bias[192 + lane];
  for (int n = gw; n < NN; n += stride) {
    const int lo = row_ptr[n], hi = row_ptr[n + 1];
    const float4 erv = *(const float4*)(er + (size_t)n * 4);
    float a0 = 0.f, a1 = 0.f, a2 = 0.f, a3 = 0.f;
    float z0 = 0.f, z1 = 0.f, z2 = 0.f, z3 = 0.f;
    for (int base = lo; base < hi; base += 64) {
      const int m = (hi - base < 64) ? (hi - base) : 64;
      float w0 = 0.f, w1 = 0.f, w2 = 0.f, w3 = 0.f;
      int s = 0;
      if (lane < m) {
        s = col[base + lane];                       // coalesced
        const float4 elv = *(const float4*)(el + (size_t)s * 4);
        float e0 = elv.x + erv.x, e1 = elv.y + erv.y;
        float e2 = elv.z + erv.z, e3 = elv.w + erv.w;
        e0 = e0 > 0.f ? e0 : NEG_SLOPE * e0;
        e1 = e1 > 0.f ? e1 : NEG_SLOPE * e1;
        e2 = e2 > 0.f ? e2 : NEG_SLOPE * e2;
        e3 = e3 > 0.f ? e3 : NEG_SLOPE * e3;
        w0 = __expf(e0); w1 = __expf(e1);
        w2 = __expf(e2); w3 = __expf(e3);
      }
      z0 += w0; z1 += w1; z2 += w2; z3 += w3;
      slds[wave][lane] = s;
      wldsv[wave][lane] = make_float4(w0, w1, w2, w3);
      for (int e = 0; e < m; ++e) {
        const int se = slds[wave][e];               // uniform -> broadcast
        const float4 wv = wldsv[wave][e];
        const uint2 d = *(const uint2*)(featb + (size_t)se * HF + lane * HH);
        const float f0 = __uint_as_float(d.x << 16);
        const float f1 = __uint_as_float(d.x & 0xFFFF0000u);
        const float f2 = __uint_as_float(d.y << 16);
        const float f3 = __uint_as_float(d.y & 0xFFFF0000u);
        a0 = fmaf(wv.x, f0, a0);
        a1 = fmaf(wv.y, f1, a1);
        a2 = fmaf(wv.z, f2, a2);
        a3 = fmaf(wv.w, f3, a3);
      }
    }
#pragma unroll
    for (int off = 1; off < 64; off <<= 1) {
      z0 += __shfl_xor(z0, off, 64);
      z1 += __shfl_xor(z1, off, 64);
      z2 += __shfl_xor(z2, off, 64);
      z3 += __shfl_xor(z3, off, 64);
    }
    unsigned short* rp = rstb + (size_t)n * HF + lane;  // [n][h*64+f]
    rp[0]   = f32_to_bf16_rne((z0 > 0.f ? a0 / z0 : 0.f) + gb0);
    rp[64]  = f32_to_bf16_rne((z1 > 0.f ? a1 / z1 : 0.f) + gb1);
    rp[128] = f32_to_bf16_rne((z2 > 0.f ? a2 / z2 : 0.f) + gb2);
    rp[192] = f32_to_bf16_rne((z3 > 0.f ? a3 / z3 : 0.f) + gb3);
  }
}

// ---------------- pack out_w into MFMA B-fragment order --------------------
__global__ __launch_bounds__(256) void k_packw(const float* __restrict__ out_w,
                                               unsigned short* __restrict__ wpack) {
  const int idx = blockIdx.x * 256 + threadIdx.x;
  if (idx >= WPACK_N) return;
  const int j = idx & 7;
  const int l = (idx >> 3) & 63;
  const int t = (idx >> 9) & 7;
  const int ct = idx >> 12;
  const int k = 32 * t + (l >> 4) * 8 + j;
  const int c = 16 * ct + (l & 15);
  wpack[idx] = f32_to_bf16_rne(out_w[k * FF + c]);
}

// ---------------- Kernel D: x = rstb @ out_w + out_b ; LayerNorm (MFMA) ----
__global__ __launch_bounds__(256) void k_out(
    const unsigned short* __restrict__ rstb,
    const unsigned short* __restrict__ wpack,
    const float* __restrict__ out_b, const float* __restrict__ ln_g,
    const float* __restrict__ ln_b, float* __restrict__ out) {
  __shared__ unsigned short wlds[WPACK_N];  // 32 KB
  {
    const uint4* src = (const uint4*)wpack;
    uint4* dstp = (uint4*)wlds;
    for (int i = threadIdx.x; i < 2048; i += 256) dstp[i] = src[i];
  }
  __syncthreads();
  const int wave = threadIdx.x >> 6;
  const int lane = threadIdx.x & 63;
  const int tile = blockIdx.x * 4 + wave;
  if (tile >= NTILE) return;
  const int n0 = tile * 16;
  const int cl = lane & 15;
  const int quad = lane >> 4;

  const unsigned short* arow = rstb + (size_t)(n0 + cl) * HF + quad * 8;
  s8v a[8];
#pragma unroll
  for (int t = 0; t < 8; ++t) a[t] = *(const s8v*)(arow + 32 * t);

  f4v acc[4];
#pragma unroll
  for (int ct = 0; ct < 4; ++ct) {
    f4v z = {0.f, 0.f, 0.f, 0.f};
    acc[ct] = z;
#pragma unroll
    for (int t = 0; t < 8; ++t) {
      const s8v b = *(const s8v*)(wlds + ((ct * 8 + t) * 64 + lane) * 8);
      acc[ct] = __builtin_amdgcn_mfma_f32_16x16x32_bf16(a[t], b, acc[ct], 0, 0, 0);
    }
  }

  float x[4][4];
  float s1[4], s2[4];
#pragma unroll
  for (int r = 0; r < 4; ++r) { s1[r] = 0.f; s2[r] = 0.f; }
#pragma unroll
  for (int ct = 0; ct < 4; ++ct) {
    const float ob = out_b[16 * ct + cl];
#pragma unroll
    for (int r = 0; r < 4; ++r) {
      const float v = acc[ct][r] + ob;
      x[ct][r] = v;
      s1[r] += v;
      s2[r] += v * v;
    }
  }
#pragma unroll
  for (int r = 0; r < 4; ++r) {
#pragma unroll
    for (int off = 1; off < 16; off <<= 1) {
      s1[r] += __shfl_xor(s1[r], off, 64);
      s2[r] += __shfl_xor(s2[r], off, 64);
    }
  }
#pragma unroll
  for (int r = 0; r < 4; ++r) {
    const float mu = s1[r] * (1.f / 64.f);
    const float var = s2[r] * (1.f / 64.f) - mu * mu;
    const float inv = rsqrtf(var + LN_EPS);
    const int row = n0 + quad * 4 + r;
#pragma unroll
    for (int ct = 0; ct < 4; ++ct) {
      const int c = 16 * ct + cl;
      out[(size_t)row * FF + c] = (x[ct][r] - mu) * inv * ln_g[c] + ln_b[c];
    }
  }
}

// ---------------- launch ---------------------------------------------------
extern "C" void kernel_launch(void* const* d_in, const int* in_sizes, int n_in,
                              void* d_out, int out_size, void* d_ws,
                              size_t ws_size, hipStream_t stream) {
  const float* h_in   = (const float*)d_in[0];
  const int*   src    = (const int*)d_in[1];
  const int*   dst    = (const int*)d_in[2];
  const float* fc_w   = (const float*)d_in[3];
  const float* attn_l = (const float*)d_in[4];
  const float* attn_r = (const float*)d_in[5];
  const float* gbias  = (const float*)d_in[6];
  const float* out_w  = (const float*)d_in[7];
  const float* out_b  = (const float*)d_in[8];
  const float* ln_g   = (const float*)d_in[9];
  const float* ln_b   = (const float*)d_in[10];
  float* out = (float*)d_out;

  char* p = (char*)d_ws;
  auto alloc = [&](size_t bytes) {
    char* q = p;
    p += (bytes + 255) & ~(size_t)255;
    return q;
  };
  unsigned short* featb  = (unsigned short*)alloc((size_t)NN * HF * 2);
  unsigned short* rstb   = (unsigned short*)alloc((size_t)NN * HF * 2);
  unsigned short* wpack  = (unsigned short*)alloc((size_t)WPACK_N * 2);
  unsigned short* wpackA = (unsigned short*)alloc((size_t)WPACKA_N * 2);
  float* el      = (float*)alloc((size_t)NN * HH * 4);
  float* er      = (float*)alloc((size_t)NN * HH * 4);
  int*   deg     = (int*)alloc((size_t)NN * 4);
  int*   row_ptr = (int*)alloc((size_t)(NN + 1) * 4);
  int*   cursor  = (int*)alloc((size_t)NN * 4);
  int*   colidx  = (int*)alloc((size_t)EE * 4);
  int*   blocksum= (int*)alloc((size_t)NB1 * 4);
  int*   blockoff= (int*)alloc((size_t)NB1 * 4);

  hipMemsetAsync(deg, 0, (size_t)NN * sizeof(int), stream);
  k_packwA<<<WPACKA_N / 256, 256, 0, stream>>>(fc_w, wpackA);
  k_packw<<<WPACK_N / 256, 256, 0, stream>>>(out_w, wpack);
  k_feat<<<(NTILE + 3) / 4, 256, 0, stream>>>(h_in, wpackA, attn_l, attn_r,
                                              featb, el, er);
  k_hist<<<(EE + 255) / 256, 256, 0, stream>>>(dst, deg);
  k_scan1<<<NB1, 256, 0, stream>>>(deg, blocksum);
  k_scan2<<<1, 256, 0, stream>>>(blocksum, blockoff);
  k_scan3<<<NB1, 256, 0, stream>>>(deg, blockoff, row_ptr, cursor);
  k_scatter<<<(EE + 255) / 256, 256, 0, stream>>>(src, dst, cursor, colidx);
  k_gather<<<2048, 256, 0, stream>>>(featb, el, er, row_ptr, colidx, gbias, rstb);
  k_out<<<(NTILE + 3) / 4, 256, 0, stream>>>(rstb, wpack, out_b, ln_g, ln_b, out);
}